// Round 15
// baseline (96.934 us; speedup 1.0000x reference)
//
#include <hip/hip_runtime.h>
#include <hip/hip_bf16.h>

typedef __attribute__((ext_vector_type(8))) short short8;
typedef __attribute__((ext_vector_type(4))) short s16x4;
typedef __attribute__((ext_vector_type(4))) float f32x4;

#define DIMV 512
#define NHEAD 8
#define NBATCH 8
#define NQL 1024
#define NKL 1024
// 1/sqrt(512) * log2(e): QK^T comes out pre-scaled in base-2 domain
#define QSCALE (0.04419417382415922f * 1.44269504088896340f)

__device__ __forceinline__ short f2bf(float f) {
    unsigned int u = __float_as_uint(f);
    unsigned int r = (u + 0x7fffu + ((u >> 16) & 1u)) >> 16;
    return (short)r;
}
__device__ __forceinline__ float bf2f(short s) {
    return __uint_as_float(((unsigned int)(unsigned short)s) << 16);
}
__device__ __forceinline__ unsigned cvt_pk_bf16(float a, float b) {
    unsigned r;
    asm("v_cvt_pk_bf16_f32 %0, %1, %2" : "=v"(r) : "v"(a), "v"(b));
    return r;   // low16 = bf16(a), high16 = bf16(b)
}
// async global->LDS, 16B per lane; dest = wave-uniform base + lane*16
__device__ __forceinline__ void gload16(const void* g, void* l) {
    __builtin_amdgcn_global_load_lds(
        (const __attribute__((address_space(1))) unsigned int*)g,
        (__attribute__((address_space(3))) unsigned int*)l, 16, 0, 0);
}

// ---------------- fused pre-pass: f32->bf16 convert (y=0,1) + weight transpose (y=2) ----------------
__global__ void k_pre(const float* __restrict__ Qf, const float* __restrict__ Kf,
                      short* __restrict__ Qb, short* __restrict__ Kb,
                      const float* __restrict__ w0, const float* __restrict__ w1,
                      const float* __restrict__ w2, const float* __restrict__ w3,
                      short* __restrict__ t0, short* __restrict__ t1,
                      short* __restrict__ t2, short* __restrict__ t3, int n) {
    __shared__ float tile[32][33];
    int tid = threadIdx.x;
    if (blockIdx.y < 2) {
        const float* src = blockIdx.y ? Kf : Qf;
        short* dst = blockIdx.y ? Kb : Qb;
        int i = (blockIdx.x * 256 + tid) * 4;
        if (i < n) {
            float4 v = *reinterpret_cast<const float4*>(src + i);
            s16x4 o;
            o[0] = f2bf(v.x); o[1] = f2bf(v.y); o[2] = f2bf(v.z); o[3] = f2bf(v.w);
            *reinterpret_cast<s16x4*>(dst + i) = o;
        }
    } else {
        int bid = blockIdx.x;
        if (bid >= 1024) return;
        int z = bid >> 8, t16 = bid & 255;
        const float* W; short* Wt;
        if (z == 0)      { W = w0; Wt = t0; }
        else if (z == 1) { W = w1; Wt = t1; }
        else if (z == 2) { W = w2; Wt = t2; }
        else             { W = w3; Wt = t3; }
        int tx = tid & 31, ty = tid >> 5;             // 32 x 8
        int n0 = (t16 & 15) * 32, k0 = (t16 >> 4) * 32;
        #pragma unroll
        for (int r = 0; r < 4; ++r)
            tile[ty + r * 8][tx] = W[(size_t)(k0 + ty + r * 8) * DIMV + n0 + tx];
        __syncthreads();
        #pragma unroll
        for (int r = 0; r < 4; ++r)
            Wt[(size_t)(n0 + ty + r * 8) * DIMV + k0 + tx] = f2bf(tile[tx][ty + r * 8]);
    }
}

// ---------------- merged Q / KV projection GEMM (global_load_lds staging) ----------------
// BM=128, BN=128, BK=64; 8 waves (2x4), wave tile 64x32, acc[4][2]; 768 blocks.
__global__ __launch_bounds__(512) void k_gemm_qkv(
    const short* __restrict__ Qb, const short* __restrict__ Kb,
    const short* __restrict__ Wqt, const short* __restrict__ Wkvt,
    const float* __restrict__ bq, const float* __restrict__ bk,
    const float* __restrict__ bv,
    short* __restrict__ Qpb, short* __restrict__ Kp, short* __restrict__ VT)
{
    __shared__ __align__(16) short As[2][128 * 64];
    __shared__ __align__(16) short Bs[2][128 * 64];
    int tid = threadIdx.x;
    int lane = tid & 63, wv = tid >> 6;          // 8 waves
    int wr = wv >> 2, wc = wv & 3;               // 2 x 4
    int c = lane & 15, g = lane >> 4;
    int bid = blockIdx.x;
    bool isQ = bid < 256;
    int lb = isQ ? bid : bid - 256;
    int NBX = isQ ? 4 : 8;
    int xcd = lb & 7, slot = lb >> 3;
    int bx = slot % NBX, by = xcd + 8 * (slot / NBX);
    int m0 = by * 128, n0 = bx * 128;
    const short* Ab = isQ ? Qb : Kb;
    const short* Bt = isQ ? Wqt : Wkvt;

    int lr = lane >> 3, ls = lane & 7;
    int sg = ls ^ lr;
    const short* Asrc = Ab + (size_t)(m0 + wv * 16 + lr) * 512 + sg * 8;
    const short* Bsrc = Bt + (size_t)(n0 + wv * 16 + lr) * 512 + sg * 8;

    #define STAGE_QKV(buf, k0)  do {                                          \
        _Pragma("unroll")                                                     \
        for (int L = 0; L < 2; ++L)                                           \
            gload16(Asrc + (k0) + L * 8 * 512, (char*)&As[buf][(wv*16+L*8)*64]);\
        _Pragma("unroll")                                                     \
        for (int L = 0; L < 2; ++L)                                           \
            gload16(Bsrc + (k0) + L * 8 * 512, (char*)&Bs[buf][(wv*16+L*8)*64]);\
    } while (0)

    STAGE_QKV(0, 0);
    __syncthreads();

    f32x4 acc[4][2] = {};
    for (int t = 0; t < 8; ++t) {
        int cur = t & 1;
        if (t < 7) STAGE_QKV(cur ^ 1, (t + 1) * 64);
        #pragma unroll
        for (int ks = 0; ks < 2; ++ks) {
            int sl = ((ks * 4 + g) ^ (c & 7)) * 8;
            short8 af[4], bf[2];
            #pragma unroll
            for (int i = 0; i < 4; ++i)
                af[i] = *reinterpret_cast<short8*>(&As[cur][(wr * 64 + i * 16 + c) * 64 + sl]);
            #pragma unroll
            for (int j = 0; j < 2; ++j)
                bf[j] = *reinterpret_cast<short8*>(&Bs[cur][(wc * 32 + j * 16 + c) * 64 + sl]);
            #pragma unroll
            for (int i = 0; i < 4; ++i)
                #pragma unroll
                for (int j = 0; j < 2; ++j)
                    acc[i][j] = __builtin_amdgcn_mfma_f32_16x16x32_bf16(af[i], bf[j], acc[i][j], 0, 0, 0);
        }
        __syncthreads();
    }

    int vb = m0 >> 10, kvb = m0 & 1023;
    #pragma unroll
    for (int i = 0; i < 4; ++i)
        #pragma unroll
        for (int j = 0; j < 2; ++j) {
            int rrow = wr * 64 + i * 16 + g * 4;
            int row = m0 + rrow;
            int col = n0 + wc * 32 + j * 16 + c;
            if (isQ) {
                float bb = bq[col];
                #pragma unroll
                for (int q = 0; q < 4; ++q)
                    Qpb[(size_t)(row + q) * 512 + col] = f2bf((acc[i][j][q] + bb) * QSCALE);
            } else if (col < 512) {
                float bb = bk[col];
                #pragma unroll
                for (int q = 0; q < 4; ++q)
                    Kp[(size_t)(row + q) * 512 + col] = f2bf(acc[i][j][q] + bb);
            } else {
                int colv = col - 512;
                float bb = bv[colv];
                s16x4 pk;
                #pragma unroll
                for (int q = 0; q < 4; ++q) pk[q] = f2bf(acc[i][j][q] + bb);
                *reinterpret_cast<s16x4*>(
                    &VT[((size_t)(vb * 512 + colv)) * 1024 + kvb + rrow]) = pk;
            }
        }
}

// ---------------- output projection GEMM (bf16 A, global_load_lds staging) ----------------
__global__ __launch_bounds__(256) void k_gemm_o(
    const short* __restrict__ A, const short* __restrict__ Bt,
    const float* __restrict__ bias, short* __restrict__ outB,
    const short* __restrict__ residB)
{
    __shared__ __align__(16) short As[2][128 * 64];
    __shared__ __align__(16) short Bs[2][64 * 64];
    int tid = threadIdx.x;
    int lane = tid & 63, wv = tid >> 6;
    int wr = wv >> 1, wc = wv & 1;
    int c = lane & 15, g = lane >> 4;
    int lb = blockIdx.x;
    int xcd = lb & 7, slot = lb >> 3;
    int bx = slot & 7, by = xcd + 8 * (slot >> 3);
    int m0 = by * 128, n0 = bx * 64;

    int lr = lane >> 3, ls = lane & 7;
    int sg = ls ^ lr;
    const short* Asrc = A + (size_t)(m0 + wv * 32 + lr) * 512 + sg * 8;
    const short* Bsrc = Bt + (size_t)(n0 + wv * 16 + lr) * 512 + sg * 8;

    #define STAGE_O(buf, k0)  do {                                            \
        _Pragma("unroll")                                                     \
        for (int L = 0; L < 4; ++L)                                           \
            gload16(Asrc + (k0) + L * 8 * 512, (char*)&As[buf][(wv*32+L*8)*64]);\
        _Pragma("unroll")                                                     \
        for (int L = 0; L < 2; ++L)                                           \
            gload16(Bsrc + (k0) + L * 8 * 512, (char*)&Bs[buf][(wv*16+L*8)*64]);\
    } while (0)

    STAGE_O(0, 0);
    __syncthreads();

    f32x4 acc[4][2] = {};
    for (int t = 0; t < 8; ++t) {
        int cur = t & 1;
        if (t < 7) STAGE_O(cur ^ 1, (t + 1) * 64);
        #pragma unroll
        for (int ks = 0; ks < 2; ++ks) {
            int sl = ((ks * 4 + g) ^ (c & 7)) * 8;
            short8 af[4], bf[2];
            #pragma unroll
            for (int i = 0; i < 4; ++i)
                af[i] = *reinterpret_cast<short8*>(&As[cur][(wr * 64 + i * 16 + c) * 64 + sl]);
            #pragma unroll
            for (int j = 0; j < 2; ++j)
                bf[j] = *reinterpret_cast<short8*>(&Bs[cur][(wc * 32 + j * 16 + c) * 64 + sl]);
            #pragma unroll
            for (int i = 0; i < 4; ++i)
                #pragma unroll
                for (int j = 0; j < 2; ++j)
                    acc[i][j] = __builtin_amdgcn_mfma_f32_16x16x32_bf16(af[i], bf[j], acc[i][j], 0, 0, 0);
        }
        __syncthreads();
    }

    #pragma unroll
    for (int i = 0; i < 4; ++i)
        #pragma unroll
        for (int j = 0; j < 2; ++j) {
            int row = m0 + wr * 64 + i * 16 + g * 4;
            int col = n0 + wc * 32 + j * 16 + c;
            float bb = bias[col];
            #pragma unroll
            for (int q = 0; q < 4; ++q) {
                size_t idx = (size_t)(row + q) * 512 + col;
                outB[idx] = f2bf(bf2f(residB[idx]) + fmaxf(acc[i][j][q] + bb, 0.f));
            }
        }
}

// ---------------- fused flash attention with residual ----------------
// 256 threads, 4 waves; each wave owns 32 q-rows (QBLK=128); KVBLK=64 dbuf.
// K/V frag reads amortized over 2 q-subtiles -> 36% fewer LDS ops per work.
__global__ __launch_bounds__(256) void k_attn(
    const short* __restrict__ Qb, const short* __restrict__ Kb,
    const short* __restrict__ VTb, const short* __restrict__ RgBase,
    short* __restrict__ Out)
{
    constexpr float RSCALE = 1.0f / QSCALE;
    __shared__ __align__(16) short Ks[2][64 * 64];
    __shared__ __align__(16) short Vt[2][64 * 64];
    __shared__ __align__(16) short Ps[128 * 72];
    int tid = threadIdx.x;
    int lane = tid & 63, wv = tid >> 6;          // 4 waves x 32 q-rows
    int c = lane & 15, g = lane >> 4;
    int bid = blockIdx.x;
    int grp = bid & 63, qb = bid >> 6;           // XCD = grp & 7
    int h = grp & 7, b = grp >> 3;
    const short* Qg = Qb + (size_t)(b * NQL + qb * 128) * 512 + h * 64;
    const short* Kg = Kb + (size_t)b * NKL * 512 + h * 64;       // stride 512
    const short* VTg = VTb + (size_t)(b * 512 + h * 64) * NKL;   // [d][kv]
    const short* Rg = RgBase + (size_t)(b * NQL + qb * 128) * 512 + h * 64;
    short* Og = Out + (size_t)(b * NQL + qb * 128) * 512 + h * 64;

    // Q fragments in registers (tile-invariant): 2 q-subtiles x 2 k-halves
    short8 qf[2][2];
    #pragma unroll
    for (int jq = 0; jq < 2; ++jq)
        #pragma unroll
        for (int ks = 0; ks < 2; ++ks)
            qf[jq][ks] = *reinterpret_cast<const short8*>(
                &Qg[(size_t)(wv * 32 + jq * 16 + c) * 512 + ks * 32 + g * 8]);

    // staging: 2 passes of 32 rows; thread (row sr, slot ss) fetches granule ss^(sr&7)
    int sr = tid >> 3, ss = tid & 7;
    int sg = ss ^ (sr & 7);
    const short* Kgc = Kg + (size_t)sr * 512 + sg * 8;
    const short* Vgc = VTg + (size_t)sr * 1024 + sg * 8;
    char* KsB = (char*)&Ks[0][0];
    char* VtB = (char*)&Vt[0][0];
    int wbase = (tid & ~63) * 16;   // wave-uniform LDS byte base (+lane*16 by HW)

    gload16(Kgc, KsB + wbase);
    gload16(Kgc + 32 * 512, KsB + 4096 + wbase);
    gload16(Vgc, VtB + wbase);
    gload16(Vgc + 32 * 1024, VtB + 4096 + wbase);
    __syncthreads();   // drains vmcnt -> buffer 0 ready

    float m[2] = {-1e30f, -1e30f}, l[2] = {0.f, 0.f};
    f32x4 o[2][4] = {};
    int swz = c & 7;

    for (int t = 0; t < 16; ++t) {
        int cur = t & 1;
        if (t < 15) {   // async prefetch next tile into the other buffer
            int nb = (cur ^ 1) * 8192;
            const short* Kn = Kgc + (size_t)(t + 1) * 64 * 512;
            const short* Vn = Vgc + (t + 1) * 64;
            gload16(Kn, KsB + nb + wbase);
            gload16(Kn + 32 * 512, KsB + nb + 4096 + wbase);
            gload16(Vn, VtB + nb + wbase);
            gload16(Vn + 32 * 1024, VtB + nb + 4096 + wbase);
        }

        // S^T = K * Q^T (pre-scaled, base-2 domain): 64kv x 32q per wave
        f32x4 s[4][2] = {};
        #pragma unroll
        for (int ks = 0; ks < 2; ++ks) {
            #pragma unroll
            for (int i = 0; i < 4; ++i) {
                short8 ak = *reinterpret_cast<short8*>(
                    &Ks[cur][(i * 16 + c) * 64 + (((ks * 4 + g) ^ swz) * 8)]);
                #pragma unroll
                for (int jq = 0; jq < 2; ++jq)
                    s[i][jq] = __builtin_amdgcn_mfma_f32_16x16x32_bf16(ak, qf[jq][ks], s[i][jq], 0, 0, 0);
            }
        }

        // online softmax per q-subtile, defer-max (THR=8 in log2 domain)
        float rowm[2];
        #pragma unroll
        for (int jq = 0; jq < 2; ++jq) {
            float r0 = fmaxf(fmaxf(s[0][jq][0], s[0][jq][1]), fmaxf(s[0][jq][2], s[0][jq][3]));
            float r1 = fmaxf(fmaxf(s[1][jq][0], s[1][jq][1]), fmaxf(s[1][jq][2], s[1][jq][3]));
            float r2 = fmaxf(fmaxf(s[2][jq][0], s[2][jq][1]), fmaxf(s[2][jq][2], s[2][jq][3]));
            float r3 = fmaxf(fmaxf(s[3][jq][0], s[3][jq][1]), fmaxf(s[3][jq][2], s[3][jq][3]));
            float rm = fmaxf(fmaxf(r0, r1), fmaxf(r2, r3));
            rm = fmaxf(rm, __shfl_xor(rm, 16));
            rm = fmaxf(rm, __shfl_xor(rm, 32));
            rowm[jq] = rm;
        }
        if (!__all((rowm[0] <= m[0] + 8.f) && (rowm[1] <= m[1] + 8.f))) {
            #pragma unroll
            for (int jq = 0; jq < 2; ++jq) {
                float mnew = fmaxf(m[jq], rowm[jq]);
                float corr = __builtin_amdgcn_exp2f(m[jq] - mnew);
                l[jq] *= corr;
                float cq[4];
                #pragma unroll
                for (int q = 0; q < 4; ++q) cq[q] = __shfl(corr, g * 4 + q);
                #pragma unroll
                for (int jf = 0; jf < 4; ++jf)
                    #pragma unroll
                    for (int q = 0; q < 4; ++q)
                        o[jq][jf][q] *= cq[q];
                m[jq] = mnew;
            }
        }
        #pragma unroll
        for (int jq = 0; jq < 2; ++jq) {
            float psum = 0.f;
            #pragma unroll
            for (int i = 0; i < 4; ++i) {
                float p0 = __builtin_amdgcn_exp2f(s[i][jq][0] - m[jq]);
                float p1 = __builtin_amdgcn_exp2f(s[i][jq][1] - m[jq]);
                float p2 = __builtin_amdgcn_exp2f(s[i][jq][2] - m[jq]);
                float p3 = __builtin_amdgcn_exp2f(s[i][jq][3] - m[jq]);
                psum += (p0 + p1) + (p2 + p3);
                uint2 pw;
                pw.x = cvt_pk_bf16(p0, p1);
                pw.y = cvt_pk_bf16(p2, p3);
                *reinterpret_cast<uint2*>(
                    &Ps[(wv * 32 + jq * 16 + c) * 72 + i * 16 + g * 4]) = pw;
            }
            psum += __shfl_xor(psum, 16);
            psum += __shfl_xor(psum, 32);
            l[jq] += psum;
        }

        // O += P * V  (V frags reused across both q-subtiles)
        #pragma unroll
        for (int ks = 0; ks < 2; ++ks) {
            short8 pa[2];
            #pragma unroll
            for (int jq = 0; jq < 2; ++jq)
                pa[jq] = *reinterpret_cast<short8*>(
                    &Ps[(wv * 32 + jq * 16 + c) * 72 + ks * 32 + g * 8]);
            #pragma unroll
            for (int jf = 0; jf < 4; ++jf) {
                short8 vb = *reinterpret_cast<short8*>(
                    &Vt[cur][(jf * 16 + c) * 64 + (((ks * 4 + g) ^ swz) * 8)]);
                #pragma unroll
                for (int jq = 0; jq < 2; ++jq)
                    o[jq][jf] = __builtin_amdgcn_mfma_f32_16x16x32_bf16(pa[jq], vb, o[jq][jf], 0, 0, 0);
            }
        }

        __syncthreads();   // all waves done with cur; drains prefetch vmcnt
    }

    #pragma unroll
    for (int jq = 0; jq < 2; ++jq) {
        float linv = 1.f / l[jq];
        float lq[4];
        #pragma unroll
        for (int q = 0; q < 4; ++q) lq[q] = __shfl(linv, g * 4 + q);
        #pragma unroll
        for (int jf = 0; jf < 4; ++jf)
            #pragma unroll
            for (int q = 0; q < 4; ++q) {
                int r = wv * 32 + jq * 16 + g * 4 + q;
                int d = jf * 16 + c;
                size_t idx = (size_t)r * 512 + d;
                Og[idx] = f2bf(o[jq][jf][q] * lq[q] + bf2f(Rg[idx]) * RSCALE);
            }
    }
}

// ---------------- LayerNorm (one wave per 512-row), bf16 input ----------------
__global__ __launch_bounds__(64) void k_ln(
    const short* __restrict__ inB,
    float* __restrict__ outF, short* __restrict__ outB,
    const float* __restrict__ gamma, const float* __restrict__ beta)
{
    int row = blockIdx.x, lane = threadIdx.x;
    float vals[8];
    short8 v = *reinterpret_cast<const short8*>(&inB[(size_t)row * 512 + lane * 8]);
    #pragma unroll
    for (int j = 0; j < 8; ++j) vals[j] = bf2f(v[j]);
    float sum = 0.f, sq = 0.f;
    #pragma unroll
    for (int j = 0; j < 8; ++j) { sum += vals[j]; sq += vals[j] * vals[j]; }
    #pragma unroll
    for (int mask = 32; mask; mask >>= 1) {
        sum += __shfl_xor(sum, mask);
        sq  += __shfl_xor(sq, mask);
    }
    float mean = sum * (1.f / 512.f);
    float var  = sq * (1.f / 512.f) - mean * mean;
    float rstd = rsqrtf(var + 1e-5f);
    float y[8];
    #pragma unroll
    for (int j = 0; j < 8; ++j) {
        int col = lane * 8 + j;
        y[j] = (vals[j] - mean) * rstd * gamma[col] + beta[col];
    }
    size_t base = (size_t)row * 512 + lane * 8;
    if (outF) {
        float4 o0 = {y[0], y[1], y[2], y[3]};
        float4 o1 = {y[4], y[5], y[6], y[7]};
        *reinterpret_cast<float4*>(&outF[base]) = o0;
        *reinterpret_cast<float4*>(&outF[base + 4]) = o1;
    }
    if (outB) {
        int4 p;
        p.x = cvt_pk_bf16(y[0], y[1]); p.y = cvt_pk_bf16(y[2], y[3]);
        p.z = cvt_pk_bf16(y[4], y[5]); p.w = cvt_pk_bf16(y[6], y[7]);
        *reinterpret_cast<int4*>(&outB[base]) = p;
    }
}

extern "C" void kernel_launch(void* const* d_in, const int* in_sizes, int n_in,
                              void* d_out, int out_size, void* d_ws, size_t ws_size,
                              hipStream_t stream) {
    const float* Q   = (const float*)d_in[0];
    const float* K   = (const float*)d_in[1];
    const float* Wq  = (const float*)d_in[2];
    const float* bq  = (const float*)d_in[3];
    const float* Wk  = (const float*)d_in[4];
    const float* bk  = (const float*)d_in[5];
    const float* Wv  = (const float*)d_in[6];
    const float* bv  = (const float*)d_in[7];
    const float* Wo  = (const float*)d_in[8];
    const float* bo  = (const float*)d_in[9];
    const float* g0  = (const float*)d_in[10];
    const float* be0 = (const float*)d_in[11];
    const float* g1  = (const float*)d_in[12];
    const float* be1 = (const float*)d_in[13];
    float* out = (float*)d_out;
    char* ws = (char*)d_ws;
    const size_t MB = 1024 * 1024;

    short* Qb    = (short*)(ws + 0);               // bf16 Q          0..8MB
    short* Kb    = (short*)(ws + 8 * MB);          // bf16 K          8..16MB
    short* Wqt   = (short*)(ws + 16 * MB);         // 512KB
    short* Wkvt  = (short*)(ws + 16 * MB + 512 * 1024);  // [1024][512] 1MB
    short* Wot   = (short*)(ws + 17 * MB + 512 * 1024);  // 512KB
    short* VT    = (short*)(ws + 18 * MB);         // per-head V^T    18..26MB
    short* Qpb   = (short*)(ws + 34 * MB);         // scaled Qp bf16  34..42MB
    short* Kp    = (short*)(ws + 42 * MB);         // K proj bf16     42..50MB
    short* Oa    = (short*)(ws + 0);               // attn out (reuses Qb)
    short* ln0b  = (short*)(ws + 34 * MB);         // reuses Qpb (dead after attn)
    short* out2b = (short*)(ws + 42 * MB);         // reuses Kp (dead after attn)

    int n = NBATCH * NQL * DIMV;  // 4194304
    dim3 pg(n / 4 / 256, 3);
    k_pre<<<pg, 256, 0, stream>>>(Q, K, Qb, Kb, Wq, Wk, Wv, Wo,
                                  Wqt, Wkvt, Wkvt + 512 * 512, Wot, n);

    k_gemm_qkv<<<768, 512, 0, stream>>>(Qb, Kb, Wqt, Wkvt, bq, bk, bv, Qpb, Kp, VT);

    k_attn<<<NBATCH * NHEAD * (NQL / 128), 256, 0, stream>>>(Qpb, Kp, VT, Qpb, Oa);

    k_ln<<<NBATCH * NQL, 64, 0, stream>>>(Oa, nullptr, ln0b, g0, be0);
    k_gemm_o<<<512, 256, 0, stream>>>(ln0b, Wot, bo, out2b, ln0b);
    k_ln<<<NBATCH * NQL, 64, 0, stream>>>(out2b, out, nullptr, g1, be1);
}

// Round 16
// 91.659 us; speedup vs baseline: 1.0576x; 1.0576x over previous
//
#include <hip/hip_runtime.h>
#include <hip/hip_bf16.h>

typedef __attribute__((ext_vector_type(8))) short short8;
typedef __attribute__((ext_vector_type(4))) short s16x4;
typedef __attribute__((ext_vector_type(4))) float f32x4;

#define DIMV 512
#define NHEAD 8
#define NBATCH 8
#define NQL 1024
#define NKL 1024
// 1/sqrt(512) * log2(e): QK^T comes out pre-scaled in base-2 domain
#define QSCALE (0.04419417382415922f * 1.44269504088896340f)

__device__ __forceinline__ short f2bf(float f) {
    unsigned int u = __float_as_uint(f);
    unsigned int r = (u + 0x7fffu + ((u >> 16) & 1u)) >> 16;
    return (short)r;
}
__device__ __forceinline__ float bf2f(short s) {
    return __uint_as_float(((unsigned int)(unsigned short)s) << 16);
}
__device__ __forceinline__ unsigned cvt_pk_bf16(float a, float b) {
    unsigned r;
    asm("v_cvt_pk_bf16_f32 %0, %1, %2" : "=v"(r) : "v"(a), "v"(b));
    return r;   // low16 = bf16(a), high16 = bf16(b)
}
// async global->LDS, 16B per lane; dest = wave-uniform base + lane*16
__device__ __forceinline__ void gload16(const void* g, void* l) {
    __builtin_amdgcn_global_load_lds(
        (const __attribute__((address_space(1))) unsigned int*)g,
        (__attribute__((address_space(3))) unsigned int*)l, 16, 0, 0);
}

// ---------------- fused pre-pass: f32->bf16 converts + weight transposes (1D grid) ----------------
// bid < 4096: Q convert; < 8192: K convert; else 1024 weight-transpose tiles.
__global__ void k_pre(const float* __restrict__ Qf, const float* __restrict__ Kf,
                      short* __restrict__ Qb, short* __restrict__ Kb,
                      const float* __restrict__ w0, const float* __restrict__ w1,
                      const float* __restrict__ w2, const float* __restrict__ w3,
                      short* __restrict__ t0, short* __restrict__ t1,
                      short* __restrict__ t2, short* __restrict__ t3, int n) {
    __shared__ float tile[32][33];
    int tid = threadIdx.x;
    int bid = blockIdx.x;
    if (bid < 8192) {
        const float* src = bid >= 4096 ? Kf : Qf;
        short* dst = bid >= 4096 ? Kb : Qb;
        int i = ((bid & 4095) * 256 + tid) * 4;
        if (i < n) {
            float4 v = *reinterpret_cast<const float4*>(src + i);
            s16x4 o;
            o[0] = f2bf(v.x); o[1] = f2bf(v.y); o[2] = f2bf(v.z); o[3] = f2bf(v.w);
            *reinterpret_cast<s16x4*>(dst + i) = o;
        }
    } else {
        int t = bid - 8192;
        int z = t >> 8, t16 = t & 255;
        const float* W; short* Wt;
        if (z == 0)      { W = w0; Wt = t0; }
        else if (z == 1) { W = w1; Wt = t1; }
        else if (z == 2) { W = w2; Wt = t2; }
        else             { W = w3; Wt = t3; }
        int tx = tid & 31, ty = tid >> 5;             // 32 x 8
        int n0 = (t16 & 15) * 32, k0 = (t16 >> 4) * 32;
        #pragma unroll
        for (int r = 0; r < 4; ++r)
            tile[ty + r * 8][tx] = W[(size_t)(k0 + ty + r * 8) * DIMV + n0 + tx];
        __syncthreads();
        #pragma unroll
        for (int r = 0; r < 4; ++r)
            Wt[(size_t)(n0 + ty + r * 8) * DIMV + k0 + tx] = f2bf(tile[tx][ty + r * 8]);
    }
}

// ---------------- merged Q / KV projection GEMM (global_load_lds staging) ----------------
// BM=128, BN=128, BK=64; 8 waves (2x4), wave tile 64x32, acc[4][2]; 768 blocks.
__global__ __launch_bounds__(512) void k_gemm_qkv(
    const short* __restrict__ Qb, const short* __restrict__ Kb,
    const short* __restrict__ Wqt, const short* __restrict__ Wkvt,
    const float* __restrict__ bq, const float* __restrict__ bk,
    const float* __restrict__ bv,
    short* __restrict__ Qpb, short* __restrict__ Kp, short* __restrict__ VT)
{
    __shared__ __align__(16) short As[2][128 * 64];
    __shared__ __align__(16) short Bs[2][128 * 64];
    int tid = threadIdx.x;
    int lane = tid & 63, wv = tid >> 6;          // 8 waves
    int wr = wv >> 2, wc = wv & 3;               // 2 x 4
    int c = lane & 15, g = lane >> 4;
    int bid = blockIdx.x;
    bool isQ = bid < 256;
    int lb = isQ ? bid : bid - 256;
    int NBX = isQ ? 4 : 8;
    int xcd = lb & 7, slot = lb >> 3;
    int bx = slot % NBX, by = xcd + 8 * (slot / NBX);
    int m0 = by * 128, n0 = bx * 128;
    const short* Ab = isQ ? Qb : Kb;
    const short* Bt = isQ ? Wqt : Wkvt;

    int lr = lane >> 3, ls = lane & 7;
    int sg = ls ^ lr;
    const short* Asrc = Ab + (size_t)(m0 + wv * 16 + lr) * 512 + sg * 8;
    const short* Bsrc = Bt + (size_t)(n0 + wv * 16 + lr) * 512 + sg * 8;

    #define STAGE_QKV(buf, k0)  do {                                          \
        _Pragma("unroll")                                                     \
        for (int L = 0; L < 2; ++L)                                           \
            gload16(Asrc + (k0) + L * 8 * 512, (char*)&As[buf][(wv*16+L*8)*64]);\
        _Pragma("unroll")                                                     \
        for (int L = 0; L < 2; ++L)                                           \
            gload16(Bsrc + (k0) + L * 8 * 512, (char*)&Bs[buf][(wv*16+L*8)*64]);\
    } while (0)

    STAGE_QKV(0, 0);
    __syncthreads();

    f32x4 acc[4][2] = {};
    for (int t = 0; t < 8; ++t) {
        int cur = t & 1;
        if (t < 7) STAGE_QKV(cur ^ 1, (t + 1) * 64);
        #pragma unroll
        for (int ks = 0; ks < 2; ++ks) {
            int sl = ((ks * 4 + g) ^ (c & 7)) * 8;
            short8 af[4], bf[2];
            #pragma unroll
            for (int i = 0; i < 4; ++i)
                af[i] = *reinterpret_cast<short8*>(&As[cur][(wr * 64 + i * 16 + c) * 64 + sl]);
            #pragma unroll
            for (int j = 0; j < 2; ++j)
                bf[j] = *reinterpret_cast<short8*>(&Bs[cur][(wc * 32 + j * 16 + c) * 64 + sl]);
            #pragma unroll
            for (int i = 0; i < 4; ++i)
                #pragma unroll
                for (int j = 0; j < 2; ++j)
                    acc[i][j] = __builtin_amdgcn_mfma_f32_16x16x32_bf16(af[i], bf[j], acc[i][j], 0, 0, 0);
        }
        __syncthreads();
    }

    int vb = m0 >> 10, kvb = m0 & 1023;
    #pragma unroll
    for (int i = 0; i < 4; ++i)
        #pragma unroll
        for (int j = 0; j < 2; ++j) {
            int rrow = wr * 64 + i * 16 + g * 4;
            int row = m0 + rrow;
            int col = n0 + wc * 32 + j * 16 + c;
            if (isQ) {
                float bb = bq[col];
                #pragma unroll
                for (int q = 0; q < 4; ++q)
                    Qpb[(size_t)(row + q) * 512 + col] = f2bf((acc[i][j][q] + bb) * QSCALE);
            } else if (col < 512) {
                float bb = bk[col];
                #pragma unroll
                for (int q = 0; q < 4; ++q)
                    Kp[(size_t)(row + q) * 512 + col] = f2bf(acc[i][j][q] + bb);
            } else {
                int colv = col - 512;
                float bb = bv[colv];
                s16x4 pk;
                #pragma unroll
                for (int q = 0; q < 4; ++q) pk[q] = f2bf(acc[i][j][q] + bb);
                *reinterpret_cast<s16x4*>(
                    &VT[((size_t)(vb * 512 + colv)) * 1024 + kvb + rrow]) = pk;
            }
        }
}

// ---------------- output projection GEMM (bf16 A, global_load_lds staging) ----------------
__global__ __launch_bounds__(256) void k_gemm_o(
    const short* __restrict__ A, const short* __restrict__ Bt,
    const float* __restrict__ bias, short* __restrict__ outB,
    const short* __restrict__ residB)
{
    __shared__ __align__(16) short As[2][128 * 64];
    __shared__ __align__(16) short Bs[2][64 * 64];
    int tid = threadIdx.x;
    int lane = tid & 63, wv = tid >> 6;
    int wr = wv >> 1, wc = wv & 1;
    int c = lane & 15, g = lane >> 4;
    int lb = blockIdx.x;
    int xcd = lb & 7, slot = lb >> 3;
    int bx = slot & 7, by = xcd + 8 * (slot >> 3);
    int m0 = by * 128, n0 = bx * 64;

    int lr = lane >> 3, ls = lane & 7;
    int sg = ls ^ lr;
    const short* Asrc = A + (size_t)(m0 + wv * 32 + lr) * 512 + sg * 8;
    const short* Bsrc = Bt + (size_t)(n0 + wv * 16 + lr) * 512 + sg * 8;

    #define STAGE_O(buf, k0)  do {                                            \
        _Pragma("unroll")                                                     \
        for (int L = 0; L < 4; ++L)                                           \
            gload16(Asrc + (k0) + L * 8 * 512, (char*)&As[buf][(wv*32+L*8)*64]);\
        _Pragma("unroll")                                                     \
        for (int L = 0; L < 2; ++L)                                           \
            gload16(Bsrc + (k0) + L * 8 * 512, (char*)&Bs[buf][(wv*16+L*8)*64]);\
    } while (0)

    STAGE_O(0, 0);
    __syncthreads();

    f32x4 acc[4][2] = {};
    for (int t = 0; t < 8; ++t) {
        int cur = t & 1;
        if (t < 7) STAGE_O(cur ^ 1, (t + 1) * 64);
        #pragma unroll
        for (int ks = 0; ks < 2; ++ks) {
            int sl = ((ks * 4 + g) ^ (c & 7)) * 8;
            short8 af[4], bf[2];
            #pragma unroll
            for (int i = 0; i < 4; ++i)
                af[i] = *reinterpret_cast<short8*>(&As[cur][(wr * 64 + i * 16 + c) * 64 + sl]);
            #pragma unroll
            for (int j = 0; j < 2; ++j)
                bf[j] = *reinterpret_cast<short8*>(&Bs[cur][(wc * 32 + j * 16 + c) * 64 + sl]);
            #pragma unroll
            for (int i = 0; i < 4; ++i)
                #pragma unroll
                for (int j = 0; j < 2; ++j)
                    acc[i][j] = __builtin_amdgcn_mfma_f32_16x16x32_bf16(af[i], bf[j], acc[i][j], 0, 0, 0);
        }
        __syncthreads();
    }

    #pragma unroll
    for (int i = 0; i < 4; ++i)
        #pragma unroll
        for (int j = 0; j < 2; ++j) {
            int row = m0 + wr * 64 + i * 16 + g * 4;
            int col = n0 + wc * 32 + j * 16 + c;
            float bb = bias[col];
            #pragma unroll
            for (int q = 0; q < 4; ++q) {
                size_t idx = (size_t)(row + q) * 512 + col;
                outB[idx] = f2bf(bf2f(residB[idx]) + fmaxf(acc[i][j][q] + bb, 0.f));
            }
        }
}

// ---------------- fused flash attention with residual (R12 structure + setprio) ----------------
// 512 threads, 8 waves; QBLK=128; KVBLK=64, double-buffered global_load_lds
// with pre-swizzled source (linear LDS dest). Softmax in exp2 domain.
__global__ __launch_bounds__(512) void k_attn(
    const short* __restrict__ Qb, const short* __restrict__ Kb,
    const short* __restrict__ VTb, const short* __restrict__ RgBase,
    short* __restrict__ Out)
{
    constexpr float RSCALE = 1.0f / QSCALE;
    __shared__ __align__(16) short Ks[2][64 * 64];
    __shared__ __align__(16) short Vt[2][64 * 64];
    __shared__ __align__(16) short Ps[128 * 72];
    int tid = threadIdx.x;
    int lane = tid & 63, w = tid >> 6;
    int c = lane & 15, g = lane >> 4;
    int bid = blockIdx.x;
    int grp = bid & 63, qb = bid >> 6;           // XCD = grp & 7
    int h = grp & 7, b = grp >> 3;
    const short* Qg = Qb + (size_t)(b * NQL + qb * 128) * 512 + h * 64;
    const short* Kg = Kb + (size_t)b * NKL * 512 + h * 64;       // stride 512
    const short* VTg = VTb + (size_t)(b * 512 + h * 64) * NKL;   // [d][kv]
    const short* Rg = RgBase + (size_t)(b * NQL + qb * 128) * 512 + h * 64;
    short* Og = Out + (size_t)(b * NQL + qb * 128) * 512 + h * 64;

    // Q fragments in registers (tile-invariant)
    short8 qf[2];
    #pragma unroll
    for (int ks = 0; ks < 2; ++ks)
        qf[ks] = *reinterpret_cast<const short8*>(&Qg[(size_t)(w * 16 + c) * 512 + ks * 32 + g * 8]);

    // staging map: thread (row sr, lds-slot ss) fetches global granule ss^(sr&7)
    int sr = tid >> 3, ss = tid & 7;
    int sg = ss ^ (sr & 7);
    const short* Kgc = Kg + (size_t)sr * 512 + sg * 8;
    const short* Vgc = VTg + (size_t)sr * 1024 + sg * 8;
    char* KsB = (char*)&Ks[0][0];
    char* VtB = (char*)&Vt[0][0];
    int wbase = (tid & ~63) * 16;   // wave-uniform LDS byte base (+lane*16 by HW)

    gload16(Kgc, KsB + wbase);
    gload16(Vgc, VtB + wbase);
    __syncthreads();   // drains vmcnt -> buffer 0 ready

    float m = -1e30f, l = 0.f;
    f32x4 o[4] = {};
    int swz = (c & 7) * 8;   // read-side XOR, in shorts

    for (int t = 0; t < 16; ++t) {
        int cur = t & 1;
        if (t < 15) {   // async prefetch next tile into the other buffer
            int nxt = cur ^ 1;
            gload16(Kgc + (size_t)(t + 1) * 64 * 512, KsB + nxt * 8192 + wbase);
            gload16(Vgc + (t + 1) * 64, VtB + nxt * 8192 + wbase);
        }

        // S^T = K * Q^T (pre-scaled, base-2 domain)
        f32x4 s[4] = {};
        __builtin_amdgcn_s_setprio(1);
        #pragma unroll
        for (int ks = 0; ks < 2; ++ks) {
            #pragma unroll
            for (int i = 0; i < 4; ++i) {
                short8 ak = *reinterpret_cast<short8*>(
                    &Ks[cur][(i * 16 + c) * 64 + (((ks * 4 + g) * 8) ^ swz)]);
                s[i] = __builtin_amdgcn_mfma_f32_16x16x32_bf16(ak, qf[ks], s[i], 0, 0, 0);
            }
        }
        __builtin_amdgcn_s_setprio(0);

        // online softmax, defer-max (THR=8 in log2 domain)
        float r0 = fmaxf(fmaxf(s[0][0], s[0][1]), fmaxf(s[0][2], s[0][3]));
        float r1 = fmaxf(fmaxf(s[1][0], s[1][1]), fmaxf(s[1][2], s[1][3]));
        float r2 = fmaxf(fmaxf(s[2][0], s[2][1]), fmaxf(s[2][2], s[2][3]));
        float r3 = fmaxf(fmaxf(s[3][0], s[3][1]), fmaxf(s[3][2], s[3][3]));
        float rowm = fmaxf(fmaxf(r0, r1), fmaxf(r2, r3));
        rowm = fmaxf(rowm, __shfl_xor(rowm, 16));
        rowm = fmaxf(rowm, __shfl_xor(rowm, 32));
        if (!__all(rowm <= m + 8.f)) {
            float mnew = fmaxf(m, rowm);
            float corr = __builtin_amdgcn_exp2f(m - mnew);
            l *= corr;
            float cq[4];
            #pragma unroll
            for (int q = 0; q < 4; ++q) cq[q] = __shfl(corr, g * 4 + q);
            #pragma unroll
            for (int jf = 0; jf < 4; ++jf)
                #pragma unroll
                for (int q = 0; q < 4; ++q)
                    o[jf][q] *= cq[q];
            m = mnew;
        }
        float psum = 0.f;
        #pragma unroll
        for (int i = 0; i < 4; ++i) {
            float p0 = __builtin_amdgcn_exp2f(s[i][0] - m);
            float p1 = __builtin_amdgcn_exp2f(s[i][1] - m);
            float p2 = __builtin_amdgcn_exp2f(s[i][2] - m);
            float p3 = __builtin_amdgcn_exp2f(s[i][3] - m);
            psum += (p0 + p1) + (p2 + p3);
            uint2 pw;
            pw.x = cvt_pk_bf16(p0, p1);
            pw.y = cvt_pk_bf16(p2, p3);
            *reinterpret_cast<uint2*>(&Ps[(w * 16 + c) * 72 + i * 16 + g * 4]) = pw;
        }
        psum += __shfl_xor(psum, 16);
        psum += __shfl_xor(psum, 32);
        l += psum;

        // O += P * V   (P rows = q, Vt[d][kv])
        __builtin_amdgcn_s_setprio(1);
        #pragma unroll
        for (int ks = 0; ks < 2; ++ks) {
            short8 pa = *reinterpret_cast<short8*>(&Ps[(w * 16 + c) * 72 + ks * 32 + g * 8]);
            #pragma unroll
            for (int jf = 0; jf < 4; ++jf) {
                short8 vb = *reinterpret_cast<short8*>(
                    &Vt[cur][(jf * 16 + c) * 64 + (((ks * 4 + g) * 8) ^ swz)]);
                o[jf] = __builtin_amdgcn_mfma_f32_16x16x32_bf16(pa, vb, o[jf], 0, 0, 0);
            }
        }
        __builtin_amdgcn_s_setprio(0);

        __syncthreads();   // all waves done with cur; drains prefetch vmcnt
    }

    float linv = 1.f / l;
    float lq[4];
    #pragma unroll
    for (int q = 0; q < 4; ++q) lq[q] = __shfl(linv, g * 4 + q);
    #pragma unroll
    for (int jf = 0; jf < 4; ++jf)
        #pragma unroll
        for (int q = 0; q < 4; ++q) {
            int r = w * 16 + g * 4 + q;
            int d = jf * 16 + c;
            size_t idx = (size_t)r * 512 + d;
            Og[idx] = f2bf(o[jf][q] * lq[q] + bf2f(Rg[idx]) * RSCALE);
        }
}

// ---------------- LayerNorm (one wave per 512-row), bf16 input ----------------
__global__ __launch_bounds__(64) void k_ln(
    const short* __restrict__ inB,
    float* __restrict__ outF, short* __restrict__ outB,
    const float* __restrict__ gamma, const float* __restrict__ beta)
{
    int row = blockIdx.x, lane = threadIdx.x;
    float vals[8];
    short8 v = *reinterpret_cast<const short8*>(&inB[(size_t)row * 512 + lane * 8]);
    #pragma unroll
    for (int j = 0; j < 8; ++j) vals[j] = bf2f(v[j]);
    float sum = 0.f, sq = 0.f;
    #pragma unroll
    for (int j = 0; j < 8; ++j) { sum += vals[j]; sq += vals[j] * vals[j]; }
    #pragma unroll
    for (int mask = 32; mask; mask >>= 1) {
        sum += __shfl_xor(sum, mask);
        sq  += __shfl_xor(sq, mask);
    }
    float mean = sum * (1.f / 512.f);
    float var  = sq * (1.f / 512.f) - mean * mean;
    float rstd = rsqrtf(var + 1e-5f);
    float y[8];
    #pragma unroll
    for (int j = 0; j < 8; ++j) {
        int col = lane * 8 + j;
        y[j] = (vals[j] - mean) * rstd * gamma[col] + beta[col];
    }
    size_t base = (size_t)row * 512 + lane * 8;
    if (outF) {
        float4 o0 = {y[0], y[1], y[2], y[3]};
        float4 o1 = {y[4], y[5], y[6], y[7]};
        *reinterpret_cast<float4*>(&outF[base]) = o0;
        *reinterpret_cast<float4*>(&outF[base + 4]) = o1;
    }
    if (outB) {
        int4 p;
        p.x = cvt_pk_bf16(y[0], y[1]); p.y = cvt_pk_bf16(y[2], y[3]);
        p.z = cvt_pk_bf16(y[4], y[5]); p.w = cvt_pk_bf16(y[6], y[7]);
        *reinterpret_cast<int4*>(&outB[base]) = p;
    }
}

extern "C" void kernel_launch(void* const* d_in, const int* in_sizes, int n_in,
                              void* d_out, int out_size, void* d_ws, size_t ws_size,
                              hipStream_t stream) {
    const float* Q   = (const float*)d_in[0];
    const float* K   = (const float*)d_in[1];
    const float* Wq  = (const float*)d_in[2];
    const float* bq  = (const float*)d_in[3];
    const float* Wk  = (const float*)d_in[4];
    const float* bk  = (const float*)d_in[5];
    const float* Wv  = (const float*)d_in[6];
    const float* bv  = (const float*)d_in[7];
    const float* Wo  = (const float*)d_in[8];
    const float* bo  = (const float*)d_in[9];
    const float* g0  = (const float*)d_in[10];
    const float* be0 = (const float*)d_in[11];
    const float* g1  = (const float*)d_in[12];
    const float* be1 = (const float*)d_in[13];
    float* out = (float*)d_out;
    char* ws = (char*)d_ws;
    const size_t MB = 1024 * 1024;

    short* Qb    = (short*)(ws + 0);               // bf16 Q          0..8MB
    short* Kb    = (short*)(ws + 8 * MB);          // bf16 K          8..16MB
    short* Wqt   = (short*)(ws + 16 * MB);         // 512KB
    short* Wkvt  = (short*)(ws + 16 * MB + 512 * 1024);  // [1024][512] 1MB
    short* Wot   = (short*)(ws + 17 * MB + 512 * 1024);  // 512KB
    short* VT    = (short*)(ws + 18 * MB);         // per-head V^T    18..26MB
    short* Qpb   = (short*)(ws + 34 * MB);         // scaled Qp bf16  34..42MB
    short* Kp    = (short*)(ws + 42 * MB);         // K proj bf16     42..50MB
    short* Oa    = (short*)(ws + 0);               // attn out (reuses Qb)
    short* ln0b  = (short*)(ws + 34 * MB);         // reuses Qpb (dead after attn)
    short* out2b = (short*)(ws + 42 * MB);         // reuses Kp (dead after attn)

    int n = NBATCH * NQL * DIMV;  // 4194304
    k_pre<<<9216, 256, 0, stream>>>(Q, K, Qb, Kb, Wq, Wk, Wv, Wo,
                                    Wqt, Wkvt, Wkvt + 512 * 512, Wot, n);

    k_gemm_qkv<<<768, 512, 0, stream>>>(Qb, Kb, Wqt, Wkvt, bq, bk, bv, Qpb, Kp, VT);

    k_attn<<<NBATCH * NHEAD * (NQL / 128), 512, 0, stream>>>(Qpb, Kp, VT, Qpb, Oa);

    k_ln<<<NBATCH * NQL, 64, 0, stream>>>(Oa, nullptr, ln0b, g0, be0);
    k_gemm_o<<<512, 256, 0, stream>>>(ln0b, Wot, bo, out2b, ln0b);
    k_ln<<<NBATCH * NQL, 64, 0, stream>>>(out2b, out, nullptr, g1, be1);
}